// Round 1
// 1885.005 us; speedup vs baseline: 1.1339x; 1.1339x over previous
//
#include <hip/hip_runtime.h>
#include <hip/hip_bf16.h>
#include <math.h>

#define B_ 2
#define T_ 512
#define C_ 512
#define L_ 3
#define NH_ 8
#define SD_ 65
#define AD_ 17
#define H4_ 2048
#define S_ 1536
#define D_ 64

typedef __hip_bfloat16 bf16;
typedef __bf16 bf16x8 __attribute__((ext_vector_type(8)));
typedef float f32x4 __attribute__((ext_vector_type(4)));

// ---- output element offsets (f32 elements) ----
#define OFF_STATE  0
#define OFF_ACTION 66560          // B*T*SD
#define OFF_RTG    83968          // + B*T*AD
#define OFF_W      84992          // + B*T
#define OFF_M      113331200ULL   // + L*B*NH*S*S
#define OUT_TOTAL  132205568ULL

// ---- workspace byte offsets (total 15,728,640 B — keep small: ws_size may be tight) ----
#define WS_HF     0ULL            // B*S*C f32 = 6,291,456
#define WS_Q      6291456ULL      // B*S*C bf16 = 3,145,728 (att reuses after scores)
#define WS_K      9437184ULL
#define WS_VT     12582912ULL     // [B,NH,D,S] bf16

// ---- convert 8 contiguous elements (bf16 or f32 source) to MFMA bf16x8 frag ----
__device__ __forceinline__ bf16x8 load8(const char* p, int is_f32) {
    if (!is_f32) return *(const bf16x8*)p;
    const float* f = (const float*)p;
    bf16x8 r;
#pragma unroll
    for (int j = 0; j < 8; j++) {
        union { __hip_bfloat16 h; __bf16 b; } u;
        u.h = __float2bfloat16(f[j]);
        r[j] = u.b;
    }
    return r;
}

__device__ __forceinline__ void block_reduce2(float& s1, float& s2, float* lds) {
    for (int off = 32; off >= 1; off >>= 1) {
        s1 += __shfl_xor(s1, off, 64);
        s2 += __shfl_xor(s2, off, 64);
    }
    int wave = threadIdx.x >> 6;
    if ((threadIdx.x & 63) == 0) { lds[wave] = s1; lds[wave + 4] = s2; }
    __syncthreads();
    s1 = lds[0] + lds[1] + lds[2] + lds[3];
    s2 = lds[4] + lds[5] + lds[6] + lds[7];
}

// ---------------- embedding + LN (all params f32, straight from d_in) ----------------
__global__ __launch_bounds__(256) void embed_kernel(
    const int* __restrict__ timesteps, const int* __restrict__ states,
    const int* __restrict__ actions, const float* __restrict__ rtg,
    const float* __restrict__ Wt, const float* __restrict__ Ws, const float* __restrict__ Wa,
    const float* __restrict__ Wr_w, const float* __restrict__ Wr_b,
    const float* __restrict__ g, const float* __restrict__ bta,
    float* __restrict__ h)
{
    int bid = blockIdx.x;           // b*S + s
    int b = bid / S_, s = bid % S_;
    int t = s / 3, kind = s % 3;
    int tid = threadIdx.x;
    int bt = b * T_ + t;
    float vals[2];
    float s1 = 0.f, s2 = 0.f;
    int ts = timesteps[bt];
    for (int i = 0; i < 2; i++) {
        int c = tid + i * 256;
        float te = Wt[(size_t)ts * C_ + c];
        float v;
        if (kind == 0)
            v = rtg[bt] * Wr_w[c] + Wr_b[c] + te;
        else if (kind == 1)
            v = Ws[(size_t)states[bt] * C_ + c] + te;
        else
            v = Wa[(size_t)actions[bt] * C_ + c] + te;
        vals[i] = v; s1 += v; s2 += v * v;
    }
    __shared__ float lds[8];
    block_reduce2(s1, s2, lds);
    float mean = s1 / C_;
    float rstd = rsqrtf(s2 / C_ - mean * mean + 1e-5f);
    size_t rowoff = (size_t)bid * C_;
    for (int i = 0; i < 2; i++) {
        int c = tid + i * 256;
        h[rowoff + c] = (vals[i] - mean) * rstd * g[c] + bta[c];
    }
}

// ---------------- in-place LayerNorm on h (f32) ----------------
__global__ __launch_bounds__(256) void ln_kernel(
    float* __restrict__ h, const float* __restrict__ g, const float* __restrict__ bta)
{
    int bid = blockIdx.x;
    int tid = threadIdx.x;
    size_t rowoff = (size_t)bid * C_;
    float vals[2]; float s1 = 0.f, s2 = 0.f;
    for (int i = 0; i < 2; i++) {
        float v = h[rowoff + tid + i * 256];
        vals[i] = v; s1 += v; s2 += v * v;
    }
    __shared__ float lds[8];
    block_reduce2(s1, s2, lds);
    float mean = s1 / C_;
    float rstd = rsqrtf(s2 / C_ - mean * mean + 1e-5f);
    for (int i = 0; i < 2; i++) {
        int c = tid + i * 256;
        h[rowoff + c] = (vals[i] - mean) * rstd * g[c] + bta[c];
    }
}

// ---------------- generic GEMM: out = A[M,K] @ W[N,K]^T (+bias) ----------------
// A and W may each be bf16 or f32 (flags). bias is f32 (or null).
// epi 0: bf16 row-major out      epi 1: transposed bf16 write to vT[b,h,d,s]
// epi 2: f32 in-place resid add: out_f32[idx] = acc + bias + out_f32[idx]
// epi 3: gelu -> f32 out
__global__ __launch_bounds__(256) void gemm_bt_kernel(
    const char* __restrict__ A, int a_f32, const char* __restrict__ W, int w_f32,
    const float* __restrict__ bias, int M, int N, int K, int epi,
    bf16* __restrict__ out_bf, float* __restrict__ out_f32)
{
    int tid = threadIdx.x;
    int wave = tid >> 6, lane = tid & 63;
    int quad = lane >> 4, l16 = lane & 15;
    int m0 = blockIdx.y * 64 + (wave >> 1) * 32;
    int n0 = blockIdx.x * 64 + (wave & 1) * 32;
    f32x4 acc[2][2] = {};
    size_t ea = a_f32 ? 4 : 2, ew = w_f32 ? 4 : 2;
    const char* Arow0 = A + ((size_t)(m0 + l16) * K + quad * 8) * ea;
    const char* Arow1 = Arow0 + (size_t)16 * K * ea;
    const char* Wrow0 = W + ((size_t)(n0 + l16) * K + quad * 8) * ew;
    const char* Wrow1 = Wrow0 + (size_t)16 * K * ew;
    for (int k0 = 0; k0 < K; k0 += 32) {
        bf16x8 a0 = load8(Arow0 + (size_t)k0 * ea, a_f32);
        bf16x8 a1 = load8(Arow1 + (size_t)k0 * ea, a_f32);
        bf16x8 b0 = load8(Wrow0 + (size_t)k0 * ew, w_f32);
        bf16x8 b1 = load8(Wrow1 + (size_t)k0 * ew, w_f32);
        acc[0][0] = __builtin_amdgcn_mfma_f32_16x16x32_bf16(a0, b0, acc[0][0], 0, 0, 0);
        acc[0][1] = __builtin_amdgcn_mfma_f32_16x16x32_bf16(a0, b1, acc[0][1], 0, 0, 0);
        acc[1][0] = __builtin_amdgcn_mfma_f32_16x16x32_bf16(a1, b0, acc[1][0], 0, 0, 0);
        acc[1][1] = __builtin_amdgcn_mfma_f32_16x16x32_bf16(a1, b1, acc[1][1], 0, 0, 0);
    }
    for (int mt = 0; mt < 2; mt++)
    for (int nt = 0; nt < 2; nt++) {
        int col = n0 + nt * 16 + l16;
        float bia = bias ? bias[col] : 0.f;
        for (int r = 0; r < 4; r++) {
            int row = m0 + mt * 16 + quad * 4 + r;
            float v = acc[mt][nt][r] + bia;
            size_t idx = (size_t)row * N + col;
            if (epi == 0) {
                out_bf[idx] = __float2bfloat16(v);
            } else if (epi == 1) {
                int bb = row / S_, ss = row % S_;
                int hh = col / D_, dd = col % D_;
                out_bf[(((size_t)bb * NH_ + hh) * D_ + dd) * S_ + ss] = __float2bfloat16(v);
            } else if (epi == 2) {
                out_f32[idx] = v + out_f32[idx];
            } else {
                out_f32[idx] = 0.5f * v * (1.f + erff(v * 0.70710678f));
            }
        }
    }
}

// ---------------- fused Q/K/V projection: one dispatch, 3x the blocks ----------------
// blockIdx.x: 24 n-blocks; chunk = nb>>3 selects {Q,K,V}; V goes transposed to vT.
__global__ __launch_bounds__(256) void qkv_kernel(
    const float* __restrict__ A,
    const float* __restrict__ Wq, const float* __restrict__ bq,
    const float* __restrict__ Wk, const float* __restrict__ bk,
    const float* __restrict__ Wv, const float* __restrict__ bv,
    bf16* __restrict__ q_bf, bf16* __restrict__ k_bf, bf16* __restrict__ vT)
{
    int tid = threadIdx.x;
    int wave = tid >> 6, lane = tid & 63;
    int quad = lane >> 4, l16 = lane & 15;
    int nb = blockIdx.x;
    int chunk = nb >> 3;
    int m0 = blockIdx.y * 64 + (wave >> 1) * 32;
    int n0 = (nb & 7) * 64 + (wave & 1) * 32;
    const float* W    = (chunk == 0) ? Wq : (chunk == 1) ? Wk : Wv;
    const float* bias = (chunk == 0) ? bq : (chunk == 1) ? bk : bv;
    f32x4 acc[2][2] = {};
    const float* Arow0 = A + (size_t)(m0 + l16) * C_ + quad * 8;
    const float* Arow1 = Arow0 + (size_t)16 * C_;
    const float* Wrow0 = W + (size_t)(n0 + l16) * C_ + quad * 8;
    const float* Wrow1 = Wrow0 + (size_t)16 * C_;
    for (int k0 = 0; k0 < C_; k0 += 32) {
        bf16x8 a0 = load8((const char*)(Arow0 + k0), 1);
        bf16x8 a1 = load8((const char*)(Arow1 + k0), 1);
        bf16x8 b0 = load8((const char*)(Wrow0 + k0), 1);
        bf16x8 b1 = load8((const char*)(Wrow1 + k0), 1);
        acc[0][0] = __builtin_amdgcn_mfma_f32_16x16x32_bf16(a0, b0, acc[0][0], 0, 0, 0);
        acc[0][1] = __builtin_amdgcn_mfma_f32_16x16x32_bf16(a0, b1, acc[0][1], 0, 0, 0);
        acc[1][0] = __builtin_amdgcn_mfma_f32_16x16x32_bf16(a1, b0, acc[1][0], 0, 0, 0);
        acc[1][1] = __builtin_amdgcn_mfma_f32_16x16x32_bf16(a1, b1, acc[1][1], 0, 0, 0);
    }
    bf16* out = (chunk == 0) ? q_bf : k_bf;
    for (int mt = 0; mt < 2; mt++)
    for (int nt = 0; nt < 2; nt++) {
        int col = n0 + nt * 16 + l16;
        float bia = bias[col];
        for (int r = 0; r < 4; r++) {
            int row = m0 + mt * 16 + quad * 4 + r;
            float v = acc[mt][nt][r] + bia;
            if (chunk < 2) {
                out[(size_t)row * C_ + col] = __float2bfloat16(v);
            } else {
                int bb = row / S_, ss = row % S_;
                int hh = col / D_, dd = col % D_;
                vT[(((size_t)bb * NH_ + hh) * D_ + dd) * S_ + ss] = __float2bfloat16(v);
            }
        }
    }
}

// ---------------- attention scores + softmax -> w (f32, into d_out) ----------------
// Writes the FULL row (masked region written as exact 0.f) — no d_out memset needed.
__global__ __launch_bounds__(256) void attn_scores_kernel(
    const bf16* __restrict__ q, const bf16* __restrict__ k, float* __restrict__ w_out)
{
    int strip = blockIdx.x;          // 16-row strip
    int bh = blockIdx.y;             // b*NH + h
    int b = bh / NH_, h = bh % NH_;
    int s0 = strip * 16;
    int tid = threadIdx.x;
    int wave = tid >> 6, lane = tid & 63, quad = lane >> 4, l16 = lane & 15;
    int ja = 3 * ((s0 + 15) / 3) + 2;                // max allowed j in strip
    int jtiles = ja / 16 + 1;
    __shared__ bf16 sc[16][1552];

    const bf16* qrow = q + ((size_t)(b * S_ + s0 + l16)) * C_ + h * D_ + quad * 8;
    bf16x8 a0 = *(const bf16x8*)(qrow);
    bf16x8 a1 = *(const bf16x8*)(qrow + 32);
    for (int jt = wave; jt < jtiles; jt += 4) {
        const bf16* krow = k + ((size_t)(b * S_ + jt * 16 + l16)) * C_ + h * D_ + quad * 8;
        bf16x8 b0 = *(const bf16x8*)(krow);
        bf16x8 b1 = *(const bf16x8*)(krow + 32);
        f32x4 acc = {0.f, 0.f, 0.f, 0.f};
        acc = __builtin_amdgcn_mfma_f32_16x16x32_bf16(a0, b0, acc, 0, 0, 0);
        acc = __builtin_amdgcn_mfma_f32_16x16x32_bf16(a1, b1, acc, 0, 0, 0);
        for (int r = 0; r < 4; r++)
            sc[quad * 4 + r][jt * 16 + l16] = __float2bfloat16(acc[r] * 0.125f);
    }
    __syncthreads();

    // thread (r, c0) owns columns 4*c0 + {0..3} + 64*k  -> float4 stores
    int r = tid >> 4, c0 = tid & 15;
    int i = s0 + r;
    int lim = 3 * (i / 3) + 2;       // max allowed column for this row
    float m = -3.0e38f;
    for (int c = 4 * c0; c <= lim; c += 64) {
#pragma unroll
        for (int j = 0; j < 4; j++) {
            int cc = c + j;
            if (cc <= lim) m = fmaxf(m, __bfloat162float(sc[r][cc]));
        }
    }
    for (int off = 8; off >= 1; off >>= 1) m = fmaxf(m, __shfl_xor(m, off, 16));
    float sum = 0.f;
    for (int c = 4 * c0; c <= lim; c += 64) {
#pragma unroll
        for (int j = 0; j < 4; j++) {
            int cc = c + j;
            if (cc <= lim) sum += __expf(__bfloat162float(sc[r][cc]) - m);
        }
    }
    for (int off = 8; off >= 1; off >>= 1) sum += __shfl_xor(sum, off, 16);
    float inv = 1.f / sum;
    float* wrow = w_out + ((size_t)bh * S_ + i) * S_;
    for (int c = 4 * c0; c < S_; c += 64) {
        f32x4 o;
#pragma unroll
        for (int j = 0; j < 4; j++) {
            int cc = c + j;
            o[j] = (cc <= lim) ? __expf(__bfloat162float(sc[r][cc]) - m) * inv : 0.f;
        }
        *(f32x4*)(wrow + c) = o;
    }
}

// ---------------- att = w @ v  (w f32 in d_out; vT layout [B,NH,D,S]) ----------------
__global__ __launch_bounds__(256) void attn_pv_kernel(
    const float* __restrict__ w, const bf16* __restrict__ vT, bf16* __restrict__ att)
{
    int strip = blockIdx.x;          // 64-row strip
    int bh = blockIdx.y;
    int b = bh / NH_, h = bh % NH_;
    int tid = threadIdx.x;
    int wave = tid >> 6, lane = tid & 63, quad = lane >> 4, l16 = lane & 15;
    int s0 = strip * 64 + wave * 16;
    int ja = 3 * ((s0 + 15) / 3) + 2;
    int kend = ((ja + 1 + 31) / 32) * 32;
    if (kend > S_) kend = S_;
    const float* wrow = w + ((size_t)bh * S_ + s0 + l16) * S_ + quad * 8;
    const bf16* vbase = vT + ((size_t)bh * D_ + l16) * S_ + quad * 8;
    f32x4 acc[4] = {};
    for (int k0 = 0; k0 < kend; k0 += 32) {
        bf16x8 a = load8((const char*)(wrow + k0), 1);
        for (int nt = 0; nt < 4; nt++) {
            bf16x8 bv = *(const bf16x8*)(vbase + (size_t)nt * 16 * S_ + k0);
            acc[nt] = __builtin_amdgcn_mfma_f32_16x16x32_bf16(a, bv, acc[nt], 0, 0, 0);
        }
    }
    for (int nt = 0; nt < 4; nt++)
    for (int r = 0; r < 4; r++) {
        int s = s0 + quad * 4 + r;
        int d = nt * 16 + l16;
        att[((size_t)(b * S_ + s)) * C_ + h * D_ + d] = __float2bfloat16(acc[nt][r]);
    }
}

// ---------------- prediction heads (f32 weights) ----------------
__global__ __launch_bounds__(256) void heads_kernel(
    const float* __restrict__ h,
    const float* __restrict__ pr_w, const float* __restrict__ pr_b,
    const float* __restrict__ ps_w, const float* __restrict__ ps_b,
    const float* __restrict__ pa_w, const float* __restrict__ pa_b,
    float* __restrict__ out)
{
    int bid = blockIdx.x;
    int b = bid / T_, t = bid % T_;
    __shared__ float hs[C_], ha[C_];
    int tid = threadIdx.x;
    for (int i = tid; i < C_; i += 256) {
        hs[i] = h[((size_t)(b * S_ + 2 * T_ + t)) * C_ + i];   // chunk 2
        ha[i] = h[((size_t)(b * S_ + T_ + t)) * C_ + i];       // chunk 1
    }
    __syncthreads();
    if (tid < SD_) {
        float acc = ps_b[tid];
        for (int kk = 0; kk < C_; kk++) acc += ps_w[tid * C_ + kk] * hs[kk];
        out[OFF_STATE + ((size_t)(b * T_ + t)) * SD_ + tid] = acc;
    } else if (tid < SD_ + AD_) {
        int n = tid - SD_;
        float acc = pa_b[n];
        for (int kk = 0; kk < C_; kk++) acc += pa_w[n * C_ + kk] * ha[kk];
        out[OFF_ACTION + ((size_t)(b * T_ + t)) * AD_ + n] = acc;
    } else if (tid == SD_ + AD_) {
        float acc = pr_b[0];
        for (int kk = 0; kk < C_; kk++) acc += pr_w[kk] * hs[kk];
        out[OFF_RTG + (size_t)(b * T_ + t)] = acc;
    }
}

extern "C" void kernel_launch(void* const* d_in, const int* in_sizes, int n_in,
                              void* d_out, int out_size, void* d_ws, size_t ws_size,
                              hipStream_t stream) {
    const int* timesteps = (const int*)d_in[0];
    const int* states    = (const int*)d_in[1];
    const int* actions   = (const int*)d_in[2];
    const float* rtg    = (const float*)d_in[3];
    const float* Wt     = (const float*)d_in[4];
    const float* Ws     = (const float*)d_in[5];
    const float* Wa     = (const float*)d_in[6];
    const float* Wr_w   = (const float*)d_in[7];
    const float* Wr_b   = (const float*)d_in[8];
    const float* ln_e_g = (const float*)d_in[9];
    const float* ln_e_b = (const float*)d_in[10];
    const float* Wq     = (const float*)d_in[11];
    const float* bq     = (const float*)d_in[12];
    const float* Wk     = (const float*)d_in[13];
    const float* bk     = (const float*)d_in[14];
    const float* Wv     = (const float*)d_in[15];
    const float* bv     = (const float*)d_in[16];
    const float* Wo     = (const float*)d_in[17];
    const float* bo     = (const float*)d_in[18];
    const float* W1     = (const float*)d_in[19];
    const float* b1     = (const float*)d_in[20];
    const float* W2     = (const float*)d_in[21];
    const float* b2     = (const float*)d_in[22];
    const float* ln1_g  = (const float*)d_in[23];
    const float* ln1_b  = (const float*)d_in[24];
    const float* ln2_g  = (const float*)d_in[25];
    const float* ln2_b  = (const float*)d_in[26];
    const float* pr_w   = (const float*)d_in[27];
    const float* pr_b   = (const float*)d_in[28];
    const float* ps_w   = (const float*)d_in[29];
    const float* ps_b   = (const float*)d_in[30];
    const float* pa_w   = (const float*)d_in[31];
    const float* pa_b   = (const float*)d_in[32];

    float* out = (float*)d_out;
    char* ws = (char*)d_ws;
    float* h_f  = (float*)(ws + WS_HF);
    bf16* q_bf  = (bf16*)(ws + WS_Q);
    bf16* att_bf = q_bf;              // reuse: q dead once scores are built
    bf16* k_bf  = (bf16*)(ws + WS_K);
    bf16* vT    = (bf16*)(ws + WS_VT);

    const int M = B_ * S_;   // 3072

    // NOTE: no memset — attn_scores writes full w rows (masked region = exact 0.f),
    // all other output regions are fully overwritten by their kernels.

    embed_kernel<<<B_ * S_, 256, 0, stream>>>(timesteps, states, actions, rtg,
                                              Wt, Ws, Wa, Wr_w, Wr_b, ln_e_g, ln_e_b, h_f);

    for (int l = 0; l < L_; l++) {
        const float* Wq_l = Wq + (size_t)l * C_ * C_;
        const float* Wk_l = Wk + (size_t)l * C_ * C_;
        const float* Wv_l = Wv + (size_t)l * C_ * C_;
        const float* Wo_l = Wo + (size_t)l * C_ * C_;
        const float* W1_l = W1 + (size_t)l * H4_ * C_;
        const float* W2_l = W2 + (size_t)l * C_ * H4_;
        float* w_l = out + OFF_W + (size_t)l * B_ * NH_ * (size_t)S_ * S_;
        float* m_l = out + OFF_M + (size_t)l * B_ * S_ * H4_;

        qkv_kernel<<<dim3(3 * C_ / 64, M / 64), 256, 0, stream>>>(
            h_f, Wq_l, bq + l * C_, Wk_l, bk + l * C_, Wv_l, bv + l * C_,
            q_bf, k_bf, vT);

        attn_scores_kernel<<<dim3(S_ / 16, B_ * NH_), 256, 0, stream>>>(q_bf, k_bf, w_l);
        attn_pv_kernel<<<dim3(S_ / 64, B_ * NH_), 256, 0, stream>>>(w_l, vT, att_bf);

        gemm_bt_kernel<<<dim3(C_ / 64, M / 64), 256, 0, stream>>>(
            (const char*)att_bf, 0, (const char*)Wo_l, 1, bo + l * C_, M, C_, C_, 2, nullptr, h_f);
        ln_kernel<<<B_ * S_, 256, 0, stream>>>(h_f, ln1_g + l * C_, ln1_b + l * C_);

        gemm_bt_kernel<<<dim3(H4_ / 64, M / 64), 256, 0, stream>>>(
            (const char*)h_f, 1, (const char*)W1_l, 1, b1 + l * H4_, M, H4_, C_, 3, nullptr, m_l);
        gemm_bt_kernel<<<dim3(C_ / 64, M / 64), 256, 0, stream>>>(
            (const char*)m_l, 1, (const char*)W2_l, 1, b2 + l * C_, M, C_, H4_, 2, nullptr, h_f);
        ln_kernel<<<B_ * S_, 256, 0, stream>>>(h_f, ln2_g + l * C_, ln2_b + l * C_);
    }

    heads_kernel<<<B_ * T_, 256, 0, stream>>>(h_f, pr_w, pr_b, ps_w, ps_b, pa_w, pa_b, out);
}

// Round 2
// 1431.727 us; speedup vs baseline: 1.4929x; 1.3166x over previous
//
#include <hip/hip_runtime.h>
#include <hip/hip_bf16.h>
#include <math.h>

#define B_ 2
#define T_ 512
#define C_ 512
#define L_ 3
#define NH_ 8
#define SD_ 65
#define AD_ 17
#define H4_ 2048
#define S_ 1536
#define D_ 64

typedef __hip_bfloat16 bf16;
typedef __bf16 bf16x8 __attribute__((ext_vector_type(8)));
typedef __bf16 bf16x4 __attribute__((ext_vector_type(4)));
typedef float f32x4 __attribute__((ext_vector_type(4)));

// ---- output element offsets (f32 elements) ----
#define OFF_STATE  0
#define OFF_ACTION 66560          // B*T*SD
#define OFF_RTG    83968          // + B*T*AD
#define OFF_W      84992          // + B*T
#define OFF_M      113331200ULL   // + L*B*NH*S*S
#define OUT_TOTAL  132205568ULL

// ---- workspace byte offsets (total 25,165,824 B) ----
#define WS_HF     0ULL            // B*S*C f32  = 6,291,456
#define WS_HB     6291456ULL      // B*S*C bf16 = 3,145,728
#define WS_Q      9437184ULL      // B*S*C bf16 (att reuses after scores)
#define WS_K      12582912ULL
#define WS_VT     15728640ULL     // [B,NH,D,S] bf16
#define WS_WB     18874368ULL     // per-layer bf16 weights, 6,291,456 B
// Wbf element offsets: Wq 0 | Wk C^2 | Wv 2C^2 | Wo 3C^2 | W1 4C^2 | W2 4C^2+H4*C
#define WOFF_O    (3 * C_ * C_)
#define WOFF_1    (4 * C_ * C_)
#define WOFF_2    (4 * C_ * C_ + H4_ * C_)
#define WCONV_N   (4 * C_ * C_ + 2 * H4_ * C_)   // 3,145,728 elems

// ---- convert 8 contiguous f32 elements to MFMA bf16x8 frag ----
__device__ __forceinline__ bf16x8 load8f(const float* f) {
    bf16x8 r;
#pragma unroll
    for (int j = 0; j < 8; j++) {
        union { __hip_bfloat16 h; __bf16 b; } u;
        u.h = __float2bfloat16(f[j]);
        r[j] = u.b;
    }
    return r;
}

__device__ __forceinline__ __bf16 tobf(float v) {
    union { __hip_bfloat16 h; __bf16 b; } u;
    u.h = __float2bfloat16(v);
    return u.b;
}

__device__ __forceinline__ void block_reduce2(float& s1, float& s2, float* lds) {
    for (int off = 32; off >= 1; off >>= 1) {
        s1 += __shfl_xor(s1, off, 64);
        s2 += __shfl_xor(s2, off, 64);
    }
    int wave = threadIdx.x >> 6;
    if ((threadIdx.x & 63) == 0) { lds[wave] = s1; lds[wave + 4] = s2; }
    __syncthreads();
    s1 = lds[0] + lds[1] + lds[2] + lds[3];
    s2 = lds[4] + lds[5] + lds[6] + lds[7];
}

// ---------------- per-layer weight convert: 6 f32 matrices -> bf16 ws ----------------
__global__ __launch_bounds__(256) void convw_kernel(
    const float* __restrict__ Wq, const float* __restrict__ Wk,
    const float* __restrict__ Wv, const float* __restrict__ Wo,
    const float* __restrict__ W1, const float* __restrict__ W2,
    bf16* __restrict__ dst)
{
    int i = (blockIdx.x * 256 + threadIdx.x) * 4;
    const float* src; int off;
    if      (i <     C_ * C_)            { src = Wq; off = i; }
    else if (i < 2 * C_ * C_)            { src = Wk; off = i -     C_ * C_; }
    else if (i < 3 * C_ * C_)            { src = Wv; off = i - 2 * C_ * C_; }
    else if (i < 4 * C_ * C_)            { src = Wo; off = i - 3 * C_ * C_; }
    else if (i < 4 * C_ * C_ + H4_ * C_) { src = W1; off = i - 4 * C_ * C_; }
    else                                 { src = W2; off = i - 4 * C_ * C_ - H4_ * C_; }
    f32x4 v = *(const f32x4*)(src + off);
    bf16x4 o;
#pragma unroll
    for (int j = 0; j < 4; j++) o[j] = tobf(v[j]);
    *(bf16x4*)(dst + i) = o;
}

// ---------------- embedding + LN -> h (f32) and hb (bf16) ----------------
__global__ __launch_bounds__(256) void embed_kernel(
    const int* __restrict__ timesteps, const int* __restrict__ states,
    const int* __restrict__ actions, const float* __restrict__ rtg,
    const float* __restrict__ Wt, const float* __restrict__ Ws, const float* __restrict__ Wa,
    const float* __restrict__ Wr_w, const float* __restrict__ Wr_b,
    const float* __restrict__ g, const float* __restrict__ bta,
    float* __restrict__ h, bf16* __restrict__ hb)
{
    int bid = blockIdx.x;           // b*S + s
    int b = bid / S_, s = bid % S_;
    int t = s / 3, kind = s % 3;
    int tid = threadIdx.x;
    int bt = b * T_ + t;
    float vals[2];
    float s1 = 0.f, s2 = 0.f;
    int ts = timesteps[bt];
    for (int i = 0; i < 2; i++) {
        int c = tid + i * 256;
        float te = Wt[(size_t)ts * C_ + c];
        float v;
        if (kind == 0)
            v = rtg[bt] * Wr_w[c] + Wr_b[c] + te;
        else if (kind == 1)
            v = Ws[(size_t)states[bt] * C_ + c] + te;
        else
            v = Wa[(size_t)actions[bt] * C_ + c] + te;
        vals[i] = v; s1 += v; s2 += v * v;
    }
    __shared__ float lds[8];
    block_reduce2(s1, s2, lds);
    float mean = s1 / C_;
    float rstd = rsqrtf(s2 / C_ - mean * mean + 1e-5f);
    size_t rowoff = (size_t)bid * C_;
    for (int i = 0; i < 2; i++) {
        int c = tid + i * 256;
        float o = (vals[i] - mean) * rstd * g[c] + bta[c];
        h[rowoff + c] = o;
        hb[rowoff + c] = __float2bfloat16(o);
    }
}

// ---------------- in-place LayerNorm on h (f32) + bf16 shadow ----------------
__global__ __launch_bounds__(256) void ln_kernel(
    float* __restrict__ h, const float* __restrict__ g, const float* __restrict__ bta,
    bf16* __restrict__ hb)
{
    int bid = blockIdx.x;
    int tid = threadIdx.x;
    size_t rowoff = (size_t)bid * C_;
    float vals[2]; float s1 = 0.f, s2 = 0.f;
    for (int i = 0; i < 2; i++) {
        float v = h[rowoff + tid + i * 256];
        vals[i] = v; s1 += v; s2 += v * v;
    }
    __shared__ float lds[8];
    block_reduce2(s1, s2, lds);
    float mean = s1 / C_;
    float rstd = rsqrtf(s2 / C_ - mean * mean + 1e-5f);
    for (int i = 0; i < 2; i++) {
        int c = tid + i * 256;
        float o = (vals[i] - mean) * rstd * g[c] + bta[c];
        h[rowoff + c] = o;
        hb[rowoff + c] = __float2bfloat16(o);
    }
}

// ---------------- generic GEMM: out = A[M,K] @ W[N,K]^T (+bias), W bf16 ----------------
// A may be bf16 or f32 (flag). bias f32 (or null).
// epi 0: bf16 row-major out   epi 2: f32 in-place resid add   epi 3: gelu -> f32 out
__global__ __launch_bounds__(256) void gemm_bt_kernel(
    const char* __restrict__ A, int a_f32, const bf16* __restrict__ W,
    const float* __restrict__ bias, int M, int N, int K, int epi,
    bf16* __restrict__ out_bf, float* __restrict__ out_f32)
{
    int tid = threadIdx.x;
    int wave = tid >> 6, lane = tid & 63;
    int quad = lane >> 4, l16 = lane & 15;
    int m0 = blockIdx.y * 64 + (wave >> 1) * 32;
    int n0 = blockIdx.x * 64 + (wave & 1) * 32;
    f32x4 acc[2][2] = {};
    size_t ea = a_f32 ? 4 : 2;
    const char* Arow0 = A + ((size_t)(m0 + l16) * K + quad * 8) * ea;
    const char* Arow1 = Arow0 + (size_t)16 * K * ea;
    const bf16* Wrow0 = W + (size_t)(n0 + l16) * K + quad * 8;
    const bf16* Wrow1 = Wrow0 + (size_t)16 * K;
    for (int k0 = 0; k0 < K; k0 += 32) {
        bf16x8 a0, a1;
        if (a_f32) {
            a0 = load8f((const float*)(Arow0 + (size_t)k0 * 4));
            a1 = load8f((const float*)(Arow1 + (size_t)k0 * 4));
        } else {
            a0 = *(const bf16x8*)(Arow0 + (size_t)k0 * 2);
            a1 = *(const bf16x8*)(Arow1 + (size_t)k0 * 2);
        }
        bf16x8 b0 = *(const bf16x8*)(Wrow0 + k0);
        bf16x8 b1 = *(const bf16x8*)(Wrow1 + k0);
        acc[0][0] = __builtin_amdgcn_mfma_f32_16x16x32_bf16(a0, b0, acc[0][0], 0, 0, 0);
        acc[0][1] = __builtin_amdgcn_mfma_f32_16x16x32_bf16(a0, b1, acc[0][1], 0, 0, 0);
        acc[1][0] = __builtin_amdgcn_mfma_f32_16x16x32_bf16(a1, b0, acc[1][0], 0, 0, 0);
        acc[1][1] = __builtin_amdgcn_mfma_f32_16x16x32_bf16(a1, b1, acc[1][1], 0, 0, 0);
    }
    for (int mt = 0; mt < 2; mt++)
    for (int nt = 0; nt < 2; nt++) {
        int col = n0 + nt * 16 + l16;
        float bia = bias ? bias[col] : 0.f;
        for (int r = 0; r < 4; r++) {
            int row = m0 + mt * 16 + quad * 4 + r;
            float v = acc[mt][nt][r] + bia;
            size_t idx = (size_t)row * N + col;
            if (epi == 0) {
                out_bf[idx] = __float2bfloat16(v);
            } else if (epi == 2) {
                out_f32[idx] = v + out_f32[idx];
            } else {
                out_f32[idx] = 0.5f * v * (1.f + erff(v * 0.70710678f));
            }
        }
    }
}

// ---------------- fused Q/K/V projection (bf16 A, bf16 W) ----------------
__global__ __launch_bounds__(256) void qkv_kernel(
    const bf16* __restrict__ A, const bf16* __restrict__ Wb,
    const float* __restrict__ bq, const float* __restrict__ bk, const float* __restrict__ bv,
    bf16* __restrict__ q_bf, bf16* __restrict__ k_bf, bf16* __restrict__ vT)
{
    int tid = threadIdx.x;
    int wave = tid >> 6, lane = tid & 63;
    int quad = lane >> 4, l16 = lane & 15;
    int nb = blockIdx.x;
    int chunk = nb >> 3;
    int m0 = blockIdx.y * 64 + (wave >> 1) * 32;
    int n0 = (nb & 7) * 64 + (wave & 1) * 32;
    const bf16* W    = Wb + (size_t)chunk * C_ * C_;
    const float* bias = (chunk == 0) ? bq : (chunk == 1) ? bk : bv;
    f32x4 acc[2][2] = {};
    const bf16* Arow0 = A + (size_t)(m0 + l16) * C_ + quad * 8;
    const bf16* Arow1 = Arow0 + (size_t)16 * C_;
    const bf16* Wrow0 = W + (size_t)(n0 + l16) * C_ + quad * 8;
    const bf16* Wrow1 = Wrow0 + (size_t)16 * C_;
    for (int k0 = 0; k0 < C_; k0 += 32) {
        bf16x8 a0 = *(const bf16x8*)(Arow0 + k0);
        bf16x8 a1 = *(const bf16x8*)(Arow1 + k0);
        bf16x8 b0 = *(const bf16x8*)(Wrow0 + k0);
        bf16x8 b1 = *(const bf16x8*)(Wrow1 + k0);
        acc[0][0] = __builtin_amdgcn_mfma_f32_16x16x32_bf16(a0, b0, acc[0][0], 0, 0, 0);
        acc[0][1] = __builtin_amdgcn_mfma_f32_16x16x32_bf16(a0, b1, acc[0][1], 0, 0, 0);
        acc[1][0] = __builtin_amdgcn_mfma_f32_16x16x32_bf16(a1, b0, acc[1][0], 0, 0, 0);
        acc[1][1] = __builtin_amdgcn_mfma_f32_16x16x32_bf16(a1, b1, acc[1][1], 0, 0, 0);
    }
    bf16* out = (chunk == 0) ? q_bf : k_bf;
    for (int mt = 0; mt < 2; mt++)
    for (int nt = 0; nt < 2; nt++) {
        int col = n0 + nt * 16 + l16;
        float bia = bias[col];
        for (int r = 0; r < 4; r++) {
            int row = m0 + mt * 16 + quad * 4 + r;
            float v = acc[mt][nt][r] + bia;
            if (chunk < 2) {
                out[(size_t)row * C_ + col] = __float2bfloat16(v);
            } else {
                int bb = row / S_, ss = row % S_;
                int hh = col / D_, dd = col % D_;
                vT[(((size_t)bb * NH_ + hh) * D_ + dd) * S_ + ss] = __float2bfloat16(v);
            }
        }
    }
}

// ---------------- fused attention: QK^T -> softmax -> write w -> PV from LDS ----------------
// One block per (16-row strip, b*NH+h). Writes full w rows (masked region exact 0.f),
// stores bf16 probs back into the LDS tile, then computes att = P @ V without re-reading w.
__global__ __launch_bounds__(256) void attn_kernel(
    const bf16* __restrict__ q, const bf16* __restrict__ k, const bf16* __restrict__ vT,
    float* __restrict__ w_out, bf16* __restrict__ att)
{
    int strip = blockIdx.x;          // 96 strips of 16 rows
    int bh = blockIdx.y;             // b*NH + h
    int b = bh / NH_, h = bh % NH_;
    int s0 = strip * 16;
    int tid = threadIdx.x;
    int wave = tid >> 6, lane = tid & 63, quad = lane >> 4, l16 = lane & 15;
    int ja = 3 * ((s0 + 15) / 3) + 2;          // max allowed column in strip
    int jtiles = ja / 16 + 1;
    int jlen32 = ((jtiles * 16) + 31) & ~31;   // PV K extent (<= 1568)
    __shared__ bf16 sc[16][1576];              // 1576 elems/row: capacity + bank stagger

    // phase 1: scores into sc (bf16, scaled)
    const bf16* qrow = q + ((size_t)(b * S_ + s0 + l16)) * C_ + h * D_ + quad * 8;
    bf16x8 a0 = *(const bf16x8*)(qrow);
    bf16x8 a1 = *(const bf16x8*)(qrow + 32);
    for (int jt = wave; jt < jtiles; jt += 4) {
        const bf16* krow = k + ((size_t)(b * S_ + jt * 16 + l16)) * C_ + h * D_ + quad * 8;
        bf16x8 b0 = *(const bf16x8*)(krow);
        bf16x8 b1 = *(const bf16x8*)(krow + 32);
        f32x4 acc = {0.f, 0.f, 0.f, 0.f};
        acc = __builtin_amdgcn_mfma_f32_16x16x32_bf16(a0, b0, acc, 0, 0, 0);
        acc = __builtin_amdgcn_mfma_f32_16x16x32_bf16(a1, b1, acc, 0, 0, 0);
        for (int r = 0; r < 4; r++)
            sc[quad * 4 + r][jt * 16 + l16] = __float2bfloat16(acc[r] * 0.125f);
    }
    __syncthreads();

    // phase 2: softmax per row; write f32 w row; overwrite sc with bf16 probs (0 beyond lim)
    {
        int r = tid >> 4, c0 = (tid & 15) * 4;
        int i = s0 + r;
        int lim = 3 * (i / 3) + 2;
        float m = -3.0e38f;
        for (int c = c0; c <= lim; c += 64) {
#pragma unroll
            for (int j = 0; j < 4; j++) {
                int cc = c + j;
                if (cc <= lim) m = fmaxf(m, __bfloat162float(sc[r][cc]));
            }
        }
        for (int off = 8; off >= 1; off >>= 1) m = fmaxf(m, __shfl_xor(m, off, 16));
        float sum = 0.f;
        for (int c = c0; c <= lim; c += 64) {
#pragma unroll
            for (int j = 0; j < 4; j++) {
                int cc = c + j;
                if (cc <= lim) sum += __expf(__bfloat162float(sc[r][cc]) - m);
            }
        }
        for (int off = 8; off >= 1; off >>= 1) sum += __shfl_xor(sum, off, 16);
        float inv = 1.f / sum;
        float* wrow = w_out + ((size_t)bh * S_ + i) * S_;
        for (int c = c0; c < S_; c += 64) {
            f32x4 o;
#pragma unroll
            for (int j = 0; j < 4; j++) {
                int cc = c + j;
                o[j] = (cc <= lim) ? __expf(__bfloat162float(sc[r][cc]) - m) * inv : 0.f;
            }
            if (c < jlen32) {
                bf16x4 p;
#pragma unroll
                for (int j = 0; j < 4; j++) p[j] = tobf(o[j]);
                *(bf16x4*)(&sc[r][c]) = p;
            }
            *(f32x4*)(wrow + c) = o;
        }
    }
    __syncthreads();

    // phase 3: att[16, 64] = P[16, jlen32] @ V^T; each wave owns a 16-col d block
    const bf16* vbase = vT + ((size_t)bh * D_ + wave * 16 + l16) * S_ + quad * 8;
    const bf16* arow = &sc[l16][quad * 8];
    f32x4 acc = {0.f, 0.f, 0.f, 0.f};
    for (int k0 = 0; k0 < jlen32; k0 += 32) {
        bf16x8 a = *(const bf16x8*)(arow + k0);
        bf16x8 bv = *(const bf16x8*)(vbase + k0);
        acc = __builtin_amdgcn_mfma_f32_16x16x32_bf16(a, bv, acc, 0, 0, 0);
    }
    for (int r = 0; r < 4; r++) {
        int s = s0 + quad * 4 + r;
        int d = wave * 16 + l16;
        att[((size_t)(b * S_ + s)) * C_ + h * D_ + d] = __float2bfloat16(acc[r]);
    }
}

// ---------------- prediction heads (f32 weights) ----------------
__global__ __launch_bounds__(256) void heads_kernel(
    const float* __restrict__ h,
    const float* __restrict__ pr_w, const float* __restrict__ pr_b,
    const float* __restrict__ ps_w, const float* __restrict__ ps_b,
    const float* __restrict__ pa_w, const float* __restrict__ pa_b,
    float* __restrict__ out)
{
    int bid = blockIdx.x;
    int b = bid / T_, t = bid % T_;
    __shared__ float hs[C_], ha[C_];
    int tid = threadIdx.x;
    for (int i = tid; i < C_; i += 256) {
        hs[i] = h[((size_t)(b * S_ + 2 * T_ + t)) * C_ + i];   // chunk 2
        ha[i] = h[((size_t)(b * S_ + T_ + t)) * C_ + i];       // chunk 1
    }
    __syncthreads();
    if (tid < SD_) {
        float acc = ps_b[tid];
        for (int kk = 0; kk < C_; kk++) acc += ps_w[tid * C_ + kk] * hs[kk];
        out[OFF_STATE + ((size_t)(b * T_ + t)) * SD_ + tid] = acc;
    } else if (tid < SD_ + AD_) {
        int n = tid - SD_;
        float acc = pa_b[n];
        for (int kk = 0; kk < C_; kk++) acc += pa_w[n * C_ + kk] * ha[kk];
        out[OFF_ACTION + ((size_t)(b * T_ + t)) * AD_ + n] = acc;
    } else if (tid == SD_ + AD_) {
        float acc = pr_b[0];
        for (int kk = 0; kk < C_; kk++) acc += pr_w[kk] * hs[kk];
        out[OFF_RTG + (size_t)(b * T_ + t)] = acc;
    }
}

extern "C" void kernel_launch(void* const* d_in, const int* in_sizes, int n_in,
                              void* d_out, int out_size, void* d_ws, size_t ws_size,
                              hipStream_t stream) {
    const int* timesteps = (const int*)d_in[0];
    const int* states    = (const int*)d_in[1];
    const int* actions   = (const int*)d_in[2];
    const float* rtg    = (const float*)d_in[3];
    const float* Wt     = (const float*)d_in[4];
    const float* Ws     = (const float*)d_in[5];
    const float* Wa     = (const float*)d_in[6];
    const float* Wr_w   = (const float*)d_in[7];
    const float* Wr_b   = (const float*)d_in[8];
    const float* ln_e_g = (const float*)d_in[9];
    const float* ln_e_b = (const float*)d_in[10];
    const float* Wq     = (const float*)d_in[11];
    const float* bq     = (const float*)d_in[12];
    const float* Wk     = (const float*)d_in[13];
    const float* bk     = (const float*)d_in[14];
    const float* Wv     = (const float*)d_in[15];
    const float* bv     = (const float*)d_in[16];
    const float* Wo     = (const float*)d_in[17];
    const float* bo     = (const float*)d_in[18];
    const float* W1     = (const float*)d_in[19];
    const float* b1     = (const float*)d_in[20];
    const float* W2     = (const float*)d_in[21];
    const float* b2     = (const float*)d_in[22];
    const float* ln1_g  = (const float*)d_in[23];
    const float* ln1_b  = (const float*)d_in[24];
    const float* ln2_g  = (const float*)d_in[25];
    const float* ln2_b  = (const float*)d_in[26];
    const float* pr_w   = (const float*)d_in[27];
    const float* pr_b   = (const float*)d_in[28];
    const float* ps_w   = (const float*)d_in[29];
    const float* ps_b   = (const float*)d_in[30];
    const float* pa_w   = (const float*)d_in[31];
    const float* pa_b   = (const float*)d_in[32];

    float* out = (float*)d_out;
    char* ws = (char*)d_ws;
    float* h_f   = (float*)(ws + WS_HF);
    bf16* h_bf   = (bf16*)(ws + WS_HB);
    bf16* q_bf   = (bf16*)(ws + WS_Q);
    bf16* att_bf = q_bf;              // reuse: q dead once probs are built
    bf16* k_bf   = (bf16*)(ws + WS_K);
    bf16* vT     = (bf16*)(ws + WS_VT);
    bf16* Wbf    = (bf16*)(ws + WS_WB);

    const int M = B_ * S_;   // 3072

    embed_kernel<<<B_ * S_, 256, 0, stream>>>(timesteps, states, actions, rtg,
                                              Wt, Ws, Wa, Wr_w, Wr_b, ln_e_g, ln_e_b,
                                              h_f, h_bf);

    for (int l = 0; l < L_; l++) {
        const float* Wq_l = Wq + (size_t)l * C_ * C_;
        const float* Wk_l = Wk + (size_t)l * C_ * C_;
        const float* Wv_l = Wv + (size_t)l * C_ * C_;
        const float* Wo_l = Wo + (size_t)l * C_ * C_;
        const float* W1_l = W1 + (size_t)l * H4_ * C_;
        const float* W2_l = W2 + (size_t)l * C_ * H4_;
        float* w_l = out + OFF_W + (size_t)l * B_ * NH_ * (size_t)S_ * S_;
        float* m_l = out + OFF_M + (size_t)l * B_ * S_ * H4_;

        convw_kernel<<<WCONV_N / 4 / 256, 256, 0, stream>>>(
            Wq_l, Wk_l, Wv_l, Wo_l, W1_l, W2_l, Wbf);

        qkv_kernel<<<dim3(3 * C_ / 64, M / 64), 256, 0, stream>>>(
            h_bf, Wbf, bq + l * C_, bk + l * C_, bv + l * C_, q_bf, k_bf, vT);

        attn_kernel<<<dim3(S_ / 16, B_ * NH_), 256, 0, stream>>>(q_bf, k_bf, vT, w_l, att_bf);

        gemm_bt_kernel<<<dim3(C_ / 64, M / 64), 256, 0, stream>>>(
            (const char*)att_bf, 0, Wbf + WOFF_O, bo + l * C_, M, C_, C_, 2, nullptr, h_f);
        ln_kernel<<<B_ * S_, 256, 0, stream>>>(h_f, ln1_g + l * C_, ln1_b + l * C_, h_bf);

        gemm_bt_kernel<<<dim3(H4_ / 64, M / 64), 256, 0, stream>>>(
            (const char*)h_bf, 0, Wbf + WOFF_1, b1 + l * H4_, M, H4_, C_, 3, nullptr, m_l);
        gemm_bt_kernel<<<dim3(C_ / 64, M / 64), 256, 0, stream>>>(
            (const char*)m_l, 1, Wbf + WOFF_2, b2 + l * C_, M, C_, H4_, 2, nullptr, h_f);
        ln_kernel<<<B_ * S_, 256, 0, stream>>>(h_f, ln2_g + l * C_, ln2_b + l * C_, h_bf);
    }

    heads_kernel<<<B_ * T_, 256, 0, stream>>>(h_f, pr_w, pr_b, ps_w, ps_b, pa_w, pa_b, out);
}

// Round 3
// 1149.315 us; speedup vs baseline: 1.8598x; 1.2457x over previous
//
#include <hip/hip_runtime.h>
#include <hip/hip_bf16.h>
#include <math.h>

#define B_ 2
#define T_ 512
#define C_ 512
#define L_ 3
#define NH_ 8
#define SD_ 65
#define AD_ 17
#define H4_ 2048
#define S_ 1536
#define D_ 64

typedef __hip_bfloat16 bf16;
typedef __bf16 bf16x8 __attribute__((ext_vector_type(8)));
typedef __bf16 bf16x4 __attribute__((ext_vector_type(4)));
typedef float f32x4 __attribute__((ext_vector_type(4)));

// ---- output element offsets (f32 elements) ----
#define OFF_STATE  0
#define OFF_ACTION 66560          // B*T*SD
#define OFF_RTG    83968          // + B*T*AD
#define OFF_W      84992          // + B*T
#define OFF_M      113331200ULL   // + L*B*NH*S*S
#define OUT_TOTAL  132205568ULL

// ---- workspace byte offsets (total ~37.8 MB) ----
#define WS_HF     0ULL            // B*S*C f32  = 6,291,456
#define WS_HB     6291456ULL      // B*S*C bf16 = 3,145,728
#define WS_QK     9437184ULL      // B*S*1024 bf16 = 6,291,456 (q|k interleaved per row)
#define WS_VT     15728640ULL     // [B,NH,D,S] bf16 = 3,145,728
#define WS_WB     18874368ULL     // per-layer bf16 weights = 6,291,456
#define WS_BIAS   25165824ULL     // packed qkv bias 1536 f32 = 6,144
#define WS_MB     25171968ULL     // m bf16 [M,H4] = 12,582,912 (att_bf aliases first 3.1MB)
// Wbf element offsets: Wq 0 | Wk C^2 | Wv 2C^2 | Wo 3C^2 | W1 4C^2 | W2 4C^2+H4*C
#define WOFF_O    (3 * C_ * C_)
#define WOFF_1    (4 * C_ * C_)
#define WOFF_2    (4 * C_ * C_ + H4_ * C_)
#define WCONV_N   (4 * C_ * C_ + 2 * H4_ * C_)   // 3,145,728 elems

__device__ __forceinline__ __bf16 tobf(float v) {
    union { __hip_bfloat16 h; __bf16 b; } u;
    u.h = __float2bfloat16(v);
    return u.b;
}

// async global->LDS 16B per lane; LDS dest is wave-uniform base + lane*16
__device__ __forceinline__ void gload_lds16(const bf16* g, bf16* l) {
    __builtin_amdgcn_global_load_lds(
        (const __attribute__((address_space(1))) void*)g,
        (__attribute__((address_space(3))) void*)l,
        16, 0, 0);
}

#define MFMA_(a, b, c) __builtin_amdgcn_mfma_f32_16x16x32_bf16(a, b, c, 0, 0, 0)

__device__ __forceinline__ void block_reduce2(float& s1, float& s2, float* lds) {
    for (int off = 32; off >= 1; off >>= 1) {
        s1 += __shfl_xor(s1, off, 64);
        s2 += __shfl_xor(s2, off, 64);
    }
    int wave = threadIdx.x >> 6;
    if ((threadIdx.x & 63) == 0) { lds[wave] = s1; lds[wave + 4] = s2; }
    __syncthreads();
    s1 = lds[0] + lds[1] + lds[2] + lds[3];
    s2 = lds[4] + lds[5] + lds[6] + lds[7];
}

// ---------------- per-layer weight+bias convert to bf16 ws ----------------
__global__ __launch_bounds__(256) void convw_kernel(
    const float* __restrict__ Wq, const float* __restrict__ Wk,
    const float* __restrict__ Wv, const float* __restrict__ Wo,
    const float* __restrict__ W1, const float* __restrict__ W2,
    const float* __restrict__ bq, const float* __restrict__ bk, const float* __restrict__ bv,
    bf16* __restrict__ dst, float* __restrict__ pbias)
{
    int i = (blockIdx.x * 256 + threadIdx.x) * 4;
    const float* src; int off;
    if      (i <     C_ * C_)            { src = Wq; off = i; }
    else if (i < 2 * C_ * C_)            { src = Wk; off = i -     C_ * C_; }
    else if (i < 3 * C_ * C_)            { src = Wv; off = i - 2 * C_ * C_; }
    else if (i < 4 * C_ * C_)            { src = Wo; off = i - 3 * C_ * C_; }
    else if (i < 4 * C_ * C_ + H4_ * C_) { src = W1; off = i - 4 * C_ * C_; }
    else                                 { src = W2; off = i - 4 * C_ * C_ - H4_ * C_; }
    f32x4 v = *(const f32x4*)(src + off);
    bf16x4 o;
#pragma unroll
    for (int j = 0; j < 4; j++) o[j] = tobf(v[j]);
    *(bf16x4*)(dst + i) = o;
    if (blockIdx.x == 0) {
        for (int j = threadIdx.x; j < 3 * C_; j += 256)
            pbias[j] = (j < C_) ? bq[j] : (j < 2 * C_) ? bk[j - C_] : bv[j - 2 * C_];
    }
}

// ---------------- embedding + LN -> h (f32) and hb (bf16) ----------------
__global__ __launch_bounds__(256) void embed_kernel(
    const int* __restrict__ timesteps, const int* __restrict__ states,
    const int* __restrict__ actions, const float* __restrict__ rtg,
    const float* __restrict__ Wt, const float* __restrict__ Ws, const float* __restrict__ Wa,
    const float* __restrict__ Wr_w, const float* __restrict__ Wr_b,
    const float* __restrict__ g, const float* __restrict__ bta,
    float* __restrict__ h, bf16* __restrict__ hb)
{
    int bid = blockIdx.x;           // b*S + s
    int b = bid / S_, s = bid % S_;
    int t = s / 3, kind = s % 3;
    int tid = threadIdx.x;
    int bt = b * T_ + t;
    float vals[2];
    float s1 = 0.f, s2 = 0.f;
    int ts = timesteps[bt];
    for (int i = 0; i < 2; i++) {
        int c = tid + i * 256;
        float te = Wt[(size_t)ts * C_ + c];
        float v;
        if (kind == 0)
            v = rtg[bt] * Wr_w[c] + Wr_b[c] + te;
        else if (kind == 1)
            v = Ws[(size_t)states[bt] * C_ + c] + te;
        else
            v = Wa[(size_t)actions[bt] * C_ + c] + te;
        vals[i] = v; s1 += v; s2 += v * v;
    }
    __shared__ float lds[8];
    block_reduce2(s1, s2, lds);
    float mean = s1 / C_;
    float rstd = rsqrtf(s2 / C_ - mean * mean + 1e-5f);
    size_t rowoff = (size_t)bid * C_;
    for (int i = 0; i < 2; i++) {
        int c = tid + i * 256;
        float o = (vals[i] - mean) * rstd * g[c] + bta[c];
        h[rowoff + c] = o;
        hb[rowoff + c] = __float2bfloat16(o);
    }
}

// ---------------- in-place LayerNorm on h (f32) + bf16 shadow ----------------
__global__ __launch_bounds__(256) void ln_kernel(
    float* __restrict__ h, const float* __restrict__ g, const float* __restrict__ bta,
    bf16* __restrict__ hb)
{
    int bid = blockIdx.x;
    int tid = threadIdx.x;
    size_t rowoff = (size_t)bid * C_;
    float vals[2]; float s1 = 0.f, s2 = 0.f;
    for (int i = 0; i < 2; i++) {
        float v = h[rowoff + tid + i * 256];
        vals[i] = v; s1 += v; s2 += v * v;
    }
    __shared__ float lds[8];
    block_reduce2(s1, s2, lds);
    float mean = s1 / C_;
    float rstd = rsqrtf(s2 / C_ - mean * mean + 1e-5f);
    for (int i = 0; i < 2; i++) {
        int c = tid + i * 256;
        float o = (vals[i] - mean) * rstd * g[c] + bta[c];
        h[rowoff + c] = o;
        hb[rowoff + c] = __float2bfloat16(o);
    }
}

// ---------------- staged GEMM: out = A[M,K] @ W[N,K]^T (+bias), all bf16 ----------------
// BM=128, BN=64, BK=64, 4 waves (2x2), double-buffered LDS via global_load_lds.
// epi 0: QKV -> qk[M,1024] (col<1024) / vT transposed (col>=1024)
// epi 2: f32 in-place resid add     epi 3: gelu -> f32 out + bf16 shadow
__global__ __launch_bounds__(256) void gemm_st_kernel(
    const bf16* __restrict__ A, const bf16* __restrict__ W,
    const float* __restrict__ bias, int M, int N, int K, int epi,
    bf16* __restrict__ out_bf, bf16* __restrict__ vT,
    float* __restrict__ out_f32, bf16* __restrict__ out_bfs)
{
    __shared__ bf16 lA[2][128 * 64];
    __shared__ bf16 lB[2][64 * 64];
    int tid = threadIdx.x;
    int wave = tid >> 6, lane = tid & 63;
    int quad = lane >> 4, l16 = lane & 15;
    int m0 = blockIdx.y * 128;
    int n0 = blockIdx.x * 64;
    int lrow = lane >> 3;            // row within an 8-row chunk
    int lcol = (lane & 7) * 8;       // element col of this lane's 16B
    const bf16* Ag = A + (size_t)m0 * K;
    const bf16* Wg = W + (size_t)n0 * K;
    f32x4 acc[4][2] = {};
    int NT = K / 64;

    // prologue: stage tile 0 into buf 0
#pragma unroll
    for (int jj = 0; jj < 4; jj++) {
        int q = wave * 4 + jj;
        gload_lds16(Ag + (size_t)(q * 8 + lrow) * K + lcol, &lA[0][q * 512]);
    }
#pragma unroll
    for (int jj = 0; jj < 2; jj++) {
        int q = wave * 2 + jj;
        gload_lds16(Wg + (size_t)(q * 8 + lrow) * K + lcol, &lB[0][q * 512]);
    }
    __syncthreads();

    int rw = wave >> 1, cw = wave & 1;
    for (int t = 0; t < NT; t++) {
        int cur = t & 1, nxt = cur ^ 1;
        if (t + 1 < NT) {
            int k0 = (t + 1) * 64;
#pragma unroll
            for (int jj = 0; jj < 4; jj++) {
                int q = wave * 4 + jj;
                gload_lds16(Ag + (size_t)(q * 8 + lrow) * K + k0 + lcol, &lA[nxt][q * 512]);
            }
#pragma unroll
            for (int jj = 0; jj < 2; jj++) {
                int q = wave * 2 + jj;
                gload_lds16(Wg + (size_t)(q * 8 + lrow) * K + k0 + lcol, &lB[nxt][q * 512]);
            }
        }
#pragma unroll
        for (int ks = 0; ks < 2; ks++) {
            bf16x8 bfr0 = *(const bf16x8*)(&lB[cur][(cw * 32 + l16) * 64 + ks * 32 + quad * 8]);
            bf16x8 bfr1 = *(const bf16x8*)(&lB[cur][(cw * 32 + 16 + l16) * 64 + ks * 32 + quad * 8]);
#pragma unroll
            for (int mf = 0; mf < 4; mf++) {
                bf16x8 afr = *(const bf16x8*)(&lA[cur][(rw * 64 + mf * 16 + l16) * 64 + ks * 32 + quad * 8]);
                acc[mf][0] = MFMA_(afr, bfr0, acc[mf][0]);
                acc[mf][1] = MFMA_(afr, bfr1, acc[mf][1]);
            }
        }
        __syncthreads();   // drains vmcnt (staged loads) + lgkmcnt; protects both buffers
    }

#pragma unroll
    for (int mf = 0; mf < 4; mf++)
#pragma unroll
    for (int nf = 0; nf < 2; nf++) {
        int col = n0 + cw * 32 + nf * 16 + l16;
        float bia = bias ? bias[col] : 0.f;
#pragma unroll
        for (int r = 0; r < 4; r++) {
            int row = m0 + rw * 64 + mf * 16 + quad * 4 + r;
            float v = acc[mf][nf][r] + bia;
            if (epi == 0) {
                if (col < 1024) {
                    out_bf[(size_t)row * 1024 + col] = __float2bfloat16(v);
                } else {
                    int c = col - 1024;
                    int bb = row / S_, ss = row % S_;
                    vT[(((size_t)bb * NH_ + (c >> 6)) * D_ + (c & 63)) * S_ + ss] = __float2bfloat16(v);
                }
            } else if (epi == 2) {
                size_t idx = (size_t)row * N + col;
                out_f32[idx] = v + out_f32[idx];
            } else {
                size_t idx = (size_t)row * N + col;
                float gl = 0.5f * v * (1.f + erff(v * 0.70710678f));
                out_f32[idx] = gl;
                out_bfs[idx] = __float2bfloat16(gl);
            }
        }
    }
}

// ---------------- fused attention: QK^T -> softmax -> write w -> PV from LDS ----------------
// q/k interleaved per row in qk[M,1024]: q cols 0..511, k cols 512..1023.
__global__ __launch_bounds__(256) void attn_kernel(
    const bf16* __restrict__ qk, const bf16* __restrict__ vT,
    float* __restrict__ w_out, bf16* __restrict__ att)
{
    int strip = blockIdx.x;          // 96 strips of 16 rows
    int bh = blockIdx.y;             // b*NH + h
    int b = bh / NH_, h = bh % NH_;
    int s0 = strip * 16;
    int tid = threadIdx.x;
    int wave = tid >> 6, lane = tid & 63, quad = lane >> 4, l16 = lane & 15;
    int ja = 3 * ((s0 + 15) / 3) + 2;          // max allowed column in strip
    int jtiles = ja / 16 + 1;
    int jlen32 = ((jtiles * 16) + 31) & ~31;   // PV K extent (<= 1568)
    __shared__ bf16 sc[16][1576];              // capacity + bank stagger

    // phase 1: scores into sc (bf16, scaled)
    const bf16* qrow = qk + ((size_t)(b * S_ + s0 + l16)) * 1024 + h * D_ + quad * 8;
    bf16x8 a0 = *(const bf16x8*)(qrow);
    bf16x8 a1 = *(const bf16x8*)(qrow + 32);
    for (int jt = wave; jt < jtiles; jt += 4) {
        const bf16* krow = qk + ((size_t)(b * S_ + jt * 16 + l16)) * 1024 + 512 + h * D_ + quad * 8;
        bf16x8 b0 = *(const bf16x8*)(krow);
        bf16x8 b1 = *(const bf16x8*)(krow + 32);
        f32x4 acc = {0.f, 0.f, 0.f, 0.f};
        acc = MFMA_(a0, b0, acc);
        acc = MFMA_(a1, b1, acc);
        for (int r = 0; r < 4; r++)
            sc[quad * 4 + r][jt * 16 + l16] = __float2bfloat16(acc[r] * 0.125f);
    }
    __syncthreads();

    // phase 2: softmax per row; write f32 w row; overwrite sc with bf16 probs
    {
        int r = tid >> 4, c0 = (tid & 15) * 4;
        int i = s0 + r;
        int lim = 3 * (i / 3) + 2;
        float m = -3.0e38f;
        for (int c = c0; c <= lim; c += 64) {
#pragma unroll
            for (int j = 0; j < 4; j++) {
                int cc = c + j;
                if (cc <= lim) m = fmaxf(m, __bfloat162float(sc[r][cc]));
            }
        }
        for (int off = 8; off >= 1; off >>= 1) m = fmaxf(m, __shfl_xor(m, off, 16));
        float sum = 0.f;
        for (int c = c0; c <= lim; c += 64) {
#pragma unroll
            for (int j = 0; j < 4; j++) {
                int cc = c + j;
                if (cc <= lim) sum += __expf(__bfloat162float(sc[r][cc]) - m);
            }
        }
        for (int off = 8; off >= 1; off >>= 1) sum += __shfl_xor(sum, off, 16);
        float inv = 1.f / sum;
        float* wrow = w_out + ((size_t)bh * S_ + i) * S_;
        for (int c = c0; c < S_; c += 64) {
            f32x4 o;
#pragma unroll
            for (int j = 0; j < 4; j++) {
                int cc = c + j;
                o[j] = (cc <= lim) ? __expf(__bfloat162float(sc[r][cc]) - m) * inv : 0.f;
            }
            if (c < jlen32) {
                bf16x4 p;
#pragma unroll
                for (int j = 0; j < 4; j++) p[j] = tobf(o[j]);
                *(bf16x4*)(&sc[r][c]) = p;
            }
            *(f32x4*)(wrow + c) = o;
        }
    }
    __syncthreads();

    // phase 3: att[16, 64] = P[16, jlen32] @ V^T; each wave owns a 16-col d block
    const bf16* vbase = vT + ((size_t)bh * D_ + wave * 16 + l16) * S_ + quad * 8;
    const bf16* arow = &sc[l16][quad * 8];
    f32x4 acc = {0.f, 0.f, 0.f, 0.f};
    for (int k0 = 0; k0 < jlen32; k0 += 32) {
        bf16x8 a = *(const bf16x8*)(arow + k0);
        bf16x8 bv = *(const bf16x8*)(vbase + k0);
        acc = MFMA_(a, bv, acc);
    }
    for (int r = 0; r < 4; r++) {
        int s = s0 + quad * 4 + r;
        int d = wave * 16 + l16;
        att[((size_t)(b * S_ + s)) * C_ + h * D_ + d] = __float2bfloat16(acc[r]);
    }
}

// ---------------- prediction heads (f32 weights) ----------------
__global__ __launch_bounds__(256) void heads_kernel(
    const float* __restrict__ h,
    const float* __restrict__ pr_w, const float* __restrict__ pr_b,
    const float* __restrict__ ps_w, const float* __restrict__ ps_b,
    const float* __restrict__ pa_w, const float* __restrict__ pa_b,
    float* __restrict__ out)
{
    int bid = blockIdx.x;
    int b = bid / T_, t = bid % T_;
    __shared__ float hs[C_], ha[C_];
    int tid = threadIdx.x;
    for (int i = tid; i < C_; i += 256) {
        hs[i] = h[((size_t)(b * S_ + 2 * T_ + t)) * C_ + i];   // chunk 2
        ha[i] = h[((size_t)(b * S_ + T_ + t)) * C_ + i];       // chunk 1
    }
    __syncthreads();
    if (tid < SD_) {
        float acc = ps_b[tid];
        for (int kk = 0; kk < C_; kk++) acc += ps_w[tid * C_ + kk] * hs[kk];
        out[OFF_STATE + ((size_t)(b * T_ + t)) * SD_ + tid] = acc;
    } else if (tid < SD_ + AD_) {
        int n = tid - SD_;
        float acc = pa_b[n];
        for (int kk = 0; kk < C_; kk++) acc += pa_w[n * C_ + kk] * ha[kk];
        out[OFF_ACTION + ((size_t)(b * T_ + t)) * AD_ + n] = acc;
    } else if (tid == SD_ + AD_) {
        float acc = pr_b[0];
        for (int kk = 0; kk < C_; kk++) acc += pr_w[kk] * hs[kk];
        out[OFF_RTG + (size_t)(b * T_ + t)] = acc;
    }
}

extern "C" void kernel_launch(void* const* d_in, const int* in_sizes, int n_in,
                              void* d_out, int out_size, void* d_ws, size_t ws_size,
                              hipStream_t stream) {
    const int* timesteps = (const int*)d_in[0];
    const int* states    = (const int*)d_in[1];
    const int* actions   = (const int*)d_in[2];
    const float* rtg    = (const float*)d_in[3];
    const float* Wt     = (const float*)d_in[4];
    const float* Ws     = (const float*)d_in[5];
    const float* Wa     = (const float*)d_in[6];
    const float* Wr_w   = (const float*)d_in[7];
    const float* Wr_b   = (const float*)d_in[8];
    const float* ln_e_g = (const float*)d_in[9];
    const float* ln_e_b = (const float*)d_in[10];
    const float* Wq     = (const float*)d_in[11];
    const float* bq     = (const float*)d_in[12];
    const float* Wk     = (const float*)d_in[13];
    const float* bk     = (const float*)d_in[14];
    const float* Wv     = (const float*)d_in[15];
    const float* bv     = (const float*)d_in[16];
    const float* Wo     = (const float*)d_in[17];
    const float* bo     = (const float*)d_in[18];
    const float* W1     = (const float*)d_in[19];
    const float* b1     = (const float*)d_in[20];
    const float* W2     = (const float*)d_in[21];
    const float* b2     = (const float*)d_in[22];
    const float* ln1_g  = (const float*)d_in[23];
    const float* ln1_b  = (const float*)d_in[24];
    const float* ln2_g  = (const float*)d_in[25];
    const float* ln2_b  = (const float*)d_in[26];
    const float* pr_w   = (const float*)d_in[27];
    const float* pr_b   = (const float*)d_in[28];
    const float* ps_w   = (const float*)d_in[29];
    const float* ps_b   = (const float*)d_in[30];
    const float* pa_w   = (const float*)d_in[31];
    const float* pa_b   = (const float*)d_in[32];

    float* out = (float*)d_out;
    char* ws = (char*)d_ws;
    float* h_f   = (float*)(ws + WS_HF);
    bf16* h_bf   = (bf16*)(ws + WS_HB);
    bf16* qk_bf  = (bf16*)(ws + WS_QK);
    bf16* vT     = (bf16*)(ws + WS_VT);
    bf16* Wbf    = (bf16*)(ws + WS_WB);
    float* pbias = (float*)(ws + WS_BIAS);
    bf16* m_bf   = (bf16*)(ws + WS_MB);
    bf16* att_bf = m_bf;             // alias: att consumed by proj before ffn1 writes m_bf

    const int M = B_ * S_;   // 3072

    embed_kernel<<<B_ * S_, 256, 0, stream>>>(timesteps, states, actions, rtg,
                                              Wt, Ws, Wa, Wr_w, Wr_b, ln_e_g, ln_e_b,
                                              h_f, h_bf);

    for (int l = 0; l < L_; l++) {
        const float* Wq_l = Wq + (size_t)l * C_ * C_;
        const float* Wk_l = Wk + (size_t)l * C_ * C_;
        const float* Wv_l = Wv + (size_t)l * C_ * C_;
        const float* Wo_l = Wo + (size_t)l * C_ * C_;
        const float* W1_l = W1 + (size_t)l * H4_ * C_;
        const float* W2_l = W2 + (size_t)l * C_ * H4_;
        float* w_l = out + OFF_W + (size_t)l * B_ * NH_ * (size_t)S_ * S_;
        float* m_l = out + OFF_M + (size_t)l * B_ * S_ * H4_;

        convw_kernel<<<WCONV_N / 4 / 256, 256, 0, stream>>>(
            Wq_l, Wk_l, Wv_l, Wo_l, W1_l, W2_l,
            bq + l * C_, bk + l * C_, bv + l * C_, Wbf, pbias);

        // QKV: N=1536 over packed [Wq;Wk;Wv]
        gemm_st_kernel<<<dim3(24, 24), 256, 0, stream>>>(
            h_bf, Wbf, pbias, M, 1536, C_, 0, qk_bf, vT, nullptr, nullptr);

        attn_kernel<<<dim3(S_ / 16, B_ * NH_), 256, 0, stream>>>(qk_bf, vT, w_l, att_bf);

        gemm_st_kernel<<<dim3(8, 24), 256, 0, stream>>>(
            att_bf, Wbf + WOFF_O, bo + l * C_, M, C_, C_, 2, nullptr, nullptr, h_f, nullptr);
        ln_kernel<<<B_ * S_, 256, 0, stream>>>(h_f, ln1_g + l * C_, ln1_b + l * C_, h_bf);

        gemm_st_kernel<<<dim3(32, 24), 256, 0, stream>>>(
            h_bf, Wbf + WOFF_1, b1 + l * H4_, M, H4_, C_, 3, nullptr, nullptr, m_l, m_bf);
        gemm_st_kernel<<<dim3(8, 24), 256, 0, stream>>>(
            m_bf, Wbf + WOFF_2, b2 + l * C_, M, C_, H4_, 2, nullptr, nullptr, h_f, nullptr);
        ln_kernel<<<B_ * S_, 256, 0, stream>>>(h_f, ln2_g + l * C_, ln2_b + l * C_, h_bf);
    }

    heads_kernel<<<B_ * T_, 256, 0, stream>>>(h_f, pr_w, pr_b, ps_w, ps_b, pa_w, pa_b, out);
}

// Round 5
// 1085.269 us; speedup vs baseline: 1.9695x; 1.0590x over previous
//
#include <hip/hip_runtime.h>
#include <hip/hip_bf16.h>
#include <math.h>

#define B_ 2
#define T_ 512
#define C_ 512
#define L_ 3
#define NH_ 8
#define SD_ 65
#define AD_ 17
#define H4_ 2048
#define S_ 1536
#define D_ 64

typedef __hip_bfloat16 bf16;
typedef __bf16 bf16x8 __attribute__((ext_vector_type(8)));
typedef __bf16 bf16x4 __attribute__((ext_vector_type(4)));
typedef float f32x4 __attribute__((ext_vector_type(4)));

// ---- output element offsets (f32 elements) ----
#define OFF_STATE  0
#define OFF_ACTION 66560          // B*T*SD
#define OFF_RTG    83968          // + B*T*AD
#define OFF_W      84992          // + B*T
#define OFF_M      113331200ULL   // + L*B*NH*S*S
#define OUT_TOTAL  132205568ULL

// ---- workspace byte offsets (total ~37.8 MB) ----
#define WS_HF     0ULL            // B*S*C f32  = 6,291,456
#define WS_HB     6291456ULL      // B*S*C bf16 = 3,145,728
#define WS_QK     9437184ULL      // B*S*1024 bf16 = 6,291,456 (q|k interleaved per row)
#define WS_VT     15728640ULL     // [B,NH,D,S] bf16 = 3,145,728
#define WS_WB     18874368ULL     // per-layer bf16 weights = 6,291,456
#define WS_BIAS   25165824ULL     // packed qkv bias 1536 f32 = 6,144
#define WS_MB     25171968ULL     // m bf16 [M,H4] = 12,582,912 (att_bf aliases first 3.1MB)
// Wbf element offsets: Wq 0 | Wk C^2 | Wv 2C^2 | Wo 3C^2 | W1 4C^2 | W2 4C^2+H4*C
#define WOFF_O    (3 * C_ * C_)
#define WOFF_1    (4 * C_ * C_)
#define WOFF_2    (4 * C_ * C_ + H4_ * C_)
#define WCONV_N   (4 * C_ * C_ + 2 * H4_ * C_)   // 3,145,728 elems

__device__ __forceinline__ __bf16 tobf(float v) {
    union { __hip_bfloat16 h; __bf16 b; } u;
    u.h = __float2bfloat16(v);
    return u.b;
}

// async global->LDS 16B per lane; LDS dest is wave-uniform base + lane*16
__device__ __forceinline__ void gload_lds16(const bf16* g, bf16* l) {
    __builtin_amdgcn_global_load_lds(
        (const __attribute__((address_space(1))) void*)g,
        (__attribute__((address_space(3))) void*)l,
        16, 0, 0);
}

#define MFMA_(a, b, c) __builtin_amdgcn_mfma_f32_16x16x32_bf16(a, b, c, 0, 0, 0)

__device__ __forceinline__ void block_reduce2(float& s1, float& s2, float* lds) {
    for (int off = 32; off >= 1; off >>= 1) {
        s1 += __shfl_xor(s1, off, 64);
        s2 += __shfl_xor(s2, off, 64);
    }
    int wave = threadIdx.x >> 6;
    if ((threadIdx.x & 63) == 0) { lds[wave] = s1; lds[wave + 4] = s2; }
    __syncthreads();
    s1 = lds[0] + lds[1] + lds[2] + lds[3];
    s2 = lds[4] + lds[5] + lds[6] + lds[7];
}

// ---------------- per-layer weight+bias convert to bf16 ws ----------------
__global__ __launch_bounds__(256) void convw_kernel(
    const float* __restrict__ Wq, const float* __restrict__ Wk,
    const float* __restrict__ Wv, const float* __restrict__ Wo,
    const float* __restrict__ W1, const float* __restrict__ W2,
    const float* __restrict__ bq, const float* __restrict__ bk, const float* __restrict__ bv,
    bf16* __restrict__ dst, float* __restrict__ pbias)
{
    int i = (blockIdx.x * 256 + threadIdx.x) * 4;
    const float* src; int off;
    if      (i <     C_ * C_)            { src = Wq; off = i; }
    else if (i < 2 * C_ * C_)            { src = Wk; off = i -     C_ * C_; }
    else if (i < 3 * C_ * C_)            { src = Wv; off = i - 2 * C_ * C_; }
    else if (i < 4 * C_ * C_)            { src = Wo; off = i - 3 * C_ * C_; }
    else if (i < 4 * C_ * C_ + H4_ * C_) { src = W1; off = i - 4 * C_ * C_; }
    else                                 { src = W2; off = i - 4 * C_ * C_ - H4_ * C_; }
    f32x4 v = *(const f32x4*)(src + off);
    bf16x4 o;
#pragma unroll
    for (int j = 0; j < 4; j++) o[j] = tobf(v[j]);
    *(bf16x4*)(dst + i) = o;
    if (blockIdx.x == 0) {
        for (int j = threadIdx.x; j < 3 * C_; j += 256)
            pbias[j] = (j < C_) ? bq[j] : (j < 2 * C_) ? bk[j - C_] : bv[j - 2 * C_];
    }
}

// ---------------- embedding + LN -> h (f32) and hb (bf16) ----------------
__global__ __launch_bounds__(256) void embed_kernel(
    const int* __restrict__ timesteps, const int* __restrict__ states,
    const int* __restrict__ actions, const float* __restrict__ rtg,
    const float* __restrict__ Wt, const float* __restrict__ Ws, const float* __restrict__ Wa,
    const float* __restrict__ Wr_w, const float* __restrict__ Wr_b,
    const float* __restrict__ g, const float* __restrict__ bta,
    float* __restrict__ h, bf16* __restrict__ hb)
{
    int bid = blockIdx.x;           // b*S + s
    int b = bid / S_, s = bid % S_;
    int t = s / 3, kind = s % 3;
    int tid = threadIdx.x;
    int bt = b * T_ + t;
    float vals[2];
    float s1 = 0.f, s2 = 0.f;
    int ts = timesteps[bt];
    for (int i = 0; i < 2; i++) {
        int c = tid + i * 256;
        float te = Wt[(size_t)ts * C_ + c];
        float v;
        if (kind == 0)
            v = rtg[bt] * Wr_w[c] + Wr_b[c] + te;
        else if (kind == 1)
            v = Ws[(size_t)states[bt] * C_ + c] + te;
        else
            v = Wa[(size_t)actions[bt] * C_ + c] + te;
        vals[i] = v; s1 += v; s2 += v * v;
    }
    __shared__ float lds[8];
    block_reduce2(s1, s2, lds);
    float mean = s1 / C_;
    float rstd = rsqrtf(s2 / C_ - mean * mean + 1e-5f);
    size_t rowoff = (size_t)bid * C_;
    for (int i = 0; i < 2; i++) {
        int c = tid + i * 256;
        float o = (vals[i] - mean) * rstd * g[c] + bta[c];
        h[rowoff + c] = o;
        hb[rowoff + c] = __float2bfloat16(o);
    }
}

// ---------------- in-place LayerNorm on h (f32) + bf16 shadow ----------------
__global__ __launch_bounds__(256) void ln_kernel(
    float* __restrict__ h, const float* __restrict__ g, const float* __restrict__ bta,
    bf16* __restrict__ hb)
{
    int bid = blockIdx.x;
    int tid = threadIdx.x;
    size_t rowoff = (size_t)bid * C_;
    float vals[2]; float s1 = 0.f, s2 = 0.f;
    for (int i = 0; i < 2; i++) {
        float v = h[rowoff + tid + i * 256];
        vals[i] = v; s1 += v; s2 += v * v;
    }
    __shared__ float lds[8];
    block_reduce2(s1, s2, lds);
    float mean = s1 / C_;
    float rstd = rsqrtf(s2 / C_ - mean * mean + 1e-5f);
    for (int i = 0; i < 2; i++) {
        int c = tid + i * 256;
        float o = (vals[i] - mean) * rstd * g[c] + bta[c];
        h[rowoff + c] = o;
        hb[rowoff + c] = __float2bfloat16(o);
    }
}

// ---------------- staged GEMM: out = A[M,K] @ W[N,K]^T (+bias), all bf16 ----------------
// BM = 32*BMF (128 or 64), BN=64, BK=64, 4 waves, double-buffered LDS via global_load_lds.
// epi 0: QKV -> qk[M,1024] (n0<1024) / vT transposed via LDS (n0>=1024, BMF=4 only)
// epi 2: f32 in-place resid add     epi 3: gelu -> f32 out + bf16 shadow
template<int BMF>
__global__ __launch_bounds__(256) void gemm_st_kernel(
    const bf16* __restrict__ A, const bf16* __restrict__ W,
    const float* __restrict__ bias, int M, int N, int K, int epi,
    bf16* __restrict__ out_bf, bf16* __restrict__ vT,
    float* __restrict__ out_f32, bf16* __restrict__ out_bfs)
{
    constexpr int BM = 32 * BMF;
    __shared__ bf16 lA[2][BM * 64];
    __shared__ bf16 lB[2][64 * 64];
    int tid = threadIdx.x;
    int wave = tid >> 6, lane = tid & 63;
    int quad = lane >> 4, l16 = lane & 15;
    int m0 = blockIdx.y * BM;
    int n0 = blockIdx.x * 64;
    int lrow = lane >> 3;            // row within an 8-row chunk
    int lcol = (lane & 7) * 8;       // element col of this lane's 16B
    const bf16* Ag = A + (size_t)m0 * K;
    const bf16* Wg = W + (size_t)n0 * K;
    f32x4 acc[BMF][2] = {};
    int NT = K / 64;

    // prologue: stage tile 0 into buf 0
#pragma unroll
    for (int jj = 0; jj < BMF; jj++) {
        int q = wave * BMF + jj;
        gload_lds16(Ag + (size_t)(q * 8 + lrow) * K + lcol, &lA[0][q * 512]);
    }
#pragma unroll
    for (int jj = 0; jj < 2; jj++) {
        int q = wave * 2 + jj;
        gload_lds16(Wg + (size_t)(q * 8 + lrow) * K + lcol, &lB[0][q * 512]);
    }
    __syncthreads();

    int rw = wave >> 1, cw = wave & 1;
    for (int t = 0; t < NT; t++) {
        int cur = t & 1, nxt = cur ^ 1;
        if (t + 1 < NT) {
            int k0 = (t + 1) * 64;
#pragma unroll
            for (int jj = 0; jj < BMF; jj++) {
                int q = wave * BMF + jj;
                gload_lds16(Ag + (size_t)(q * 8 + lrow) * K + k0 + lcol, &lA[nxt][q * 512]);
            }
#pragma unroll
            for (int jj = 0; jj < 2; jj++) {
                int q = wave * 2 + jj;
                gload_lds16(Wg + (size_t)(q * 8 + lrow) * K + k0 + lcol, &lB[nxt][q * 512]);
            }
        }
#pragma unroll
        for (int ks = 0; ks < 2; ks++) {
            bf16x8 bfr0 = *(const bf16x8*)(&lB[cur][(cw * 32 + l16) * 64 + ks * 32 + quad * 8]);
            bf16x8 bfr1 = *(const bf16x8*)(&lB[cur][(cw * 32 + 16 + l16) * 64 + ks * 32 + quad * 8]);
#pragma unroll
            for (int mf = 0; mf < BMF; mf++) {
                bf16x8 afr = *(const bf16x8*)(&lA[cur][(rw * (BM / 2) + mf * 16 + l16) * 64 + ks * 32 + quad * 8]);
                acc[mf][0] = MFMA_(afr, bfr0, acc[mf][0]);
                acc[mf][1] = MFMA_(afr, bfr1, acc[mf][1]);
            }
        }
        __syncthreads();   // drains vmcnt (staged loads) + lgkmcnt; protects both buffers
    }

    if (epi == 0) {
        if constexpr (BMF == 4) {
            if (n0 >= 1024) {
                // V block: transpose 128x64 acc tile through LDS, write vT coalesced.
                // lA is dead after the loop's final barrier.
                bf16* sT = &lA[0][0];               // [64][136] d-major
#pragma unroll
                for (int mf = 0; mf < 4; mf++)
#pragma unroll
                for (int nf = 0; nf < 2; nf++) {
                    int dl = cw * 32 + nf * 16 + l16;
                    float bia = bias[n0 + dl];
#pragma unroll
                    for (int r = 0; r < 4; r++) {
                        int sl = rw * 64 + mf * 16 + quad * 4 + r;
                        sT[dl * 136 + sl] = __float2bfloat16(acc[mf][nf][r] + bia);
                    }
                }
                __syncthreads();
                int b = m0 / S_, s0 = m0 % S_;
                int h = (n0 - 1024) >> 6;
                int d = tid >> 2, qs = (tid & 3) * 32;
                bf16* dst = vT + (((size_t)b * NH_ + h) * D_ + d) * S_ + s0 + qs;
#pragma unroll
                for (int j = 0; j < 4; j++)
                    *(bf16x8*)(dst + j * 8) = *(const bf16x8*)(&sT[d * 136 + qs + j * 8]);
                return;
            }
        }
        // q/k block
#pragma unroll
        for (int mf = 0; mf < BMF; mf++)
#pragma unroll
        for (int nf = 0; nf < 2; nf++) {
            int col = n0 + cw * 32 + nf * 16 + l16;
            float bia = bias[col];
#pragma unroll
            for (int r = 0; r < 4; r++) {
                int row = m0 + rw * (BM / 2) + mf * 16 + quad * 4 + r;
                out_bf[(size_t)row * 1024 + col] = __float2bfloat16(acc[mf][nf][r] + bia);
            }
        }
        return;
    }

#pragma unroll
    for (int mf = 0; mf < BMF; mf++)
#pragma unroll
    for (int nf = 0; nf < 2; nf++) {
        int col = n0 + cw * 32 + nf * 16 + l16;
        float bia = bias ? bias[col] : 0.f;
#pragma unroll
        for (int r = 0; r < 4; r++) {
            int row = m0 + rw * (BM / 2) + mf * 16 + quad * 4 + r;
            float v = acc[mf][nf][r] + bia;
            size_t idx = (size_t)row * N + col;
            if (epi == 2) {
                out_f32[idx] = v + out_f32[idx];
            } else {
                float gl = 0.5f * v * (1.f + erff(v * 0.70710678f));
                out_f32[idx] = gl;
                out_bfs[idx] = __float2bfloat16(gl);
            }
        }
    }
}

// ---------------- fused attention: QK^T -> softmax -> write w -> PV from LDS ----------------
// q/k interleaved per row in qk[M,1024]: q cols 0..511, k cols 512..1023.
// Strips processed largest-first (strip = 95 - bx) for load balance.
__global__ __launch_bounds__(256) void attn_kernel(
    const bf16* __restrict__ qk, const bf16* __restrict__ vT,
    float* __restrict__ w_out, bf16* __restrict__ att)
{
    int strip = (S_ / 16 - 1) - blockIdx.x;    // heaviest strips dispatch first
    int bh = blockIdx.y;             // b*NH + h
    int b = bh / NH_, h = bh % NH_;
    int s0 = strip * 16;
    int tid = threadIdx.x;
    int wave = tid >> 6, lane = tid & 63, quad = lane >> 4, l16 = lane & 15;
    int ja = 3 * ((s0 + 15) / 3) + 2;          // max allowed column in strip
    int jtiles = ja / 16 + 1;
    int jlen32 = ((jtiles * 16) + 31) & ~31;   // PV K extent (<= 1568)
    __shared__ bf16 sc[16][1576];              // capacity + bank stagger

    // phase 1: scores into sc (bf16, scaled)
    const bf16* qrow = qk + ((size_t)(b * S_ + s0 + l16)) * 1024 + h * D_ + quad * 8;
    bf16x8 a0 = *(const bf16x8*)(qrow);
    bf16x8 a1 = *(const bf16x8*)(qrow + 32);
    for (int jt = wave; jt < jtiles; jt += 4) {
        const bf16* krow = qk + ((size_t)(b * S_ + jt * 16 + l16)) * 1024 + 512 + h * D_ + quad * 8;
        bf16x8 b0 = *(const bf16x8*)(krow);
        bf16x8 b1 = *(const bf16x8*)(krow + 32);
        f32x4 acc = {0.f, 0.f, 0.f, 0.f};
        acc = MFMA_(a0, b0, acc);
        acc = MFMA_(a1, b1, acc);
        for (int r = 0; r < 4; r++)
            sc[quad * 4 + r][jt * 16 + l16] = __float2bfloat16(acc[r] * 0.125f);
    }
    __syncthreads();

    // phase 2: softmax per row; write f32 w row; overwrite sc with bf16 probs
    {
        int r = tid >> 4, c0 = (tid & 15) * 4;
        int i = s0 + r;
        int lim = 3 * (i / 3) + 2;
        float m = -3.0e38f;
        for (int c = c0; c <= lim; c += 64) {
#pragma unroll
            for (int j = 0; j < 4; j++) {
                int cc = c + j;
                if (cc <= lim) m = fmaxf(m, __bfloat162float(sc[r][cc]));
            }
        }
        for (int off = 8; off >= 1; off >>= 1) m = fmaxf(m, __shfl_xor(m, off, 16));
        float sum = 0.f;
        for (int c = c0; c <= lim; c += 64) {
#pragma unroll
            for (int j = 0; j < 4; j++) {
                int cc = c + j;
                if (cc <= lim) sum += __expf(__bfloat162float(sc[r][cc]) - m);
            }
        }
        for (int off = 8; off >= 1; off >>= 1) sum += __shfl_xor(sum, off, 16);
        float inv = 1.f / sum;
        float* wrow = w_out + ((size_t)bh * S_ + i) * S_;
        for (int c = c0; c < S_; c += 64) {
            f32x4 o;
#pragma unroll
            for (int j = 0; j < 4; j++) {
                int cc = c + j;
                o[j] = (cc <= lim) ? __expf(__bfloat162float(sc[r][cc]) - m) * inv : 0.f;
            }
            if (c < jlen32) {
                bf16x4 p;
#pragma unroll
                for (int j = 0; j < 4; j++) p[j] = tobf(o[j]);
                *(bf16x4*)(&sc[r][c]) = p;
            }
            *(f32x4*)(wrow + c) = o;
        }
    }
    __syncthreads();

    // phase 3: att[16, 64] = P[16, jlen32] @ V^T; each wave owns a 16-col d block
    const bf16* vbase = vT + ((size_t)bh * D_ + wave * 16 + l16) * S_ + quad * 8;
    const bf16* arow = &sc[l16][quad * 8];
    f32x4 acc = {0.f, 0.f, 0.f, 0.f};
    for (int k0 = 0; k0 < jlen32; k0 += 32) {
        bf16x8 a = *(const bf16x8*)(arow + k0);
        bf16x8 bv = *(const bf16x8*)(vbase + k0);
        acc = MFMA_(a, bv, acc);
    }
    for (int r = 0; r < 4; r++) {
        int s = s0 + quad * 4 + r;
        int d = wave * 16 + l16;
        att[((size_t)(b * S_ + s)) * C_ + h * D_ + d] = __float2bfloat16(acc[r]);
    }
}

// ---------------- prediction heads (f32 weights) ----------------
__global__ __launch_bounds__(256) void heads_kernel(
    const float* __restrict__ h,
    const float* __restrict__ pr_w, const float* __restrict__ pr_b,
    const float* __restrict__ ps_w, const float* __restrict__ ps_b,
    const float* __restrict__ pa_w, const float* __restrict__ pa_b,
    float* __restrict__ out)
{
    int bid = blockIdx.x;
    int b = bid / T_, t = bid % T_;
    __shared__ float hs[C_], ha[C_];
    int tid = threadIdx.x;
    for (int i = tid; i < C_; i += 256) {
        hs[i] = h[((size_t)(b * S_ + 2 * T_ + t)) * C_ + i];   // chunk 2
        ha[i] = h[((size_t)(b * S_ + T_ + t)) * C_ + i];       // chunk 1
    }
    __syncthreads();
    if (tid < SD_) {
        float acc = ps_b[tid];
        for (int kk = 0; kk < C_; kk++) acc += ps_w[tid * C_ + kk] * hs[kk];
        out[OFF_STATE + ((size_t)(b * T_ + t)) * SD_ + tid] = acc;
    } else if (tid < SD_ + AD_) {
        int n = tid - SD_;
        float acc = pa_b[n];
        for (int kk = 0; kk < C_; kk++) acc += pa_w[n * C_ + kk] * ha[kk];
        out[OFF_ACTION + ((size_t)(b * T_ + t)) * AD_ + n] = acc;
    } else if (tid == SD_ + AD_) {
        float acc = pr_b[0];
        for (int kk = 0; kk < C_; kk++) acc += pr_w[kk] * hs[kk];
        out[OFF_RTG + (size_t)(b * T_ + t)] = acc;
    }
}

extern "C" void kernel_launch(void* const* d_in, const int* in_sizes, int n_in,
                              void* d_out, int out_size, void* d_ws, size_t ws_size,
                              hipStream_t stream) {
    const int* timesteps = (const int*)d_in[0];
    const int* states    = (const int*)d_in[1];
    const int* actions   = (const int*)d_in[2];
    const float* rtg    = (const float*)d_in[3];
    const float* Wt     = (const float*)d_in[4];
    const float* Ws     = (const float*)d_in[5];
    const float* Wa     = (const float*)d_in[6];
    const float* Wr_w   = (const float*)d_in[7];
    const float* Wr_b   = (const float*)d_in[8];
    const float* ln_e_g = (const float*)d_in[9];
    const float* ln_e_b = (const float*)d_in[10];
    const float* Wq     = (const float*)d_in[11];
    const float* bq     = (const float*)d_in[12];
    const float* Wk     = (const float*)d_in[13];
    const float* bk     = (const float*)d_in[14];
    const float* Wv     = (const float*)d_in[15];
    const float* bv     = (const float*)d_in[16];
    const float* Wo     = (const float*)d_in[17];
    const float* bo     = (const float*)d_in[18];
    const float* W1     = (const float*)d_in[19];
    const float* b1     = (const float*)d_in[20];
    const float* W2     = (const float*)d_in[21];
    const float* b2     = (const float*)d_in[22];
    const float* ln1_g  = (const float*)d_in[23];
    const float* ln1_b  = (const float*)d_in[24];
    const float* ln2_g  = (const float*)d_in[25];
    const float* ln2_b  = (const float*)d_in[26];
    const float* pr_w   = (const float*)d_in[27];
    const float* pr_b   = (const float*)d_in[28];
    const float* ps_w   = (const float*)d_in[29];
    const float* ps_b   = (const float*)d_in[30];
    const float* pa_w   = (const float*)d_in[31];
    const float* pa_b   = (const float*)d_in[32];

    float* out = (float*)d_out;
    char* ws = (char*)d_ws;
    float* h_f   = (float*)(ws + WS_HF);
    bf16* h_bf   = (bf16*)(ws + WS_HB);
    bf16* qk_bf  = (bf16*)(ws + WS_QK);
    bf16* vT     = (bf16*)(ws + WS_VT);
    bf16* Wbf    = (bf16*)(ws + WS_WB);
    float* pbias = (float*)(ws + WS_BIAS);
    bf16* m_bf   = (bf16*)(ws + WS_MB);
    bf16* att_bf = m_bf;             // alias: att consumed by proj before ffn1 writes m_bf

    const int M = B_ * S_;   // 3072

    embed_kernel<<<B_ * S_, 256, 0, stream>>>(timesteps, states, actions, rtg,
                                              Wt, Ws, Wa, Wr_w, Wr_b, ln_e_g, ln_e_b,
                                              h_f, h_bf);

    for (int l = 0; l < L_; l++) {
        const float* Wq_l = Wq + (size_t)l * C_ * C_;
        const float* Wk_l = Wk + (size_t)l * C_ * C_;
        const float* Wv_l = Wv + (size_t)l * C_ * C_;
        const float* Wo_l = Wo + (size_t)l * C_ * C_;
        const float* W1_l = W1 + (size_t)l * H4_ * C_;
        const float* W2_l = W2 + (size_t)l * C_ * H4_;
        float* w_l = out + OFF_W + (size_t)l * B_ * NH_ * (size_t)S_ * S_;
        float* m_l = out + OFF_M + (size_t)l * B_ * S_ * H4_;

        convw_kernel<<<WCONV_N / 4 / 256, 256, 0, stream>>>(
            Wq_l, Wk_l, Wv_l, Wo_l, W1_l, W2_l,
            bq + l * C_, bk + l * C_, bv + l * C_, Wbf, pbias);

        // QKV: N=1536 over packed [Wq;Wk;Wv], BM=128
        gemm_st_kernel<4><<<dim3(24, 24), 256, 0, stream>>>(
            h_bf, Wbf, pbias, M, 1536, C_, 0, qk_bf, vT, nullptr, nullptr);

        attn_kernel<<<dim3(S_ / 16, B_ * NH_), 256, 0, stream>>>(qk_bf, vT, w_l, att_bf);

        // proj: BM=64 (grid 8x48 = 384 blocks)
        gemm_st_kernel<2><<<dim3(8, 48), 256, 0, stream>>>(
            att_bf, Wbf + WOFF_O, bo + l * C_, M, C_, C_, 2, nullptr, nullptr, h_f, nullptr);
        ln_kernel<<<B_ * S_, 256, 0, stream>>>(h_f, ln1_g + l * C_, ln1_b + l * C_, h_bf);

        // ffn1: BM=128 (grid 32x24 = 768 blocks)
        gemm_st_kernel<4><<<dim3(32, 24), 256, 0, stream>>>(
            h_bf, Wbf + WOFF_1, b1 + l * H4_, M, H4_, C_, 3, nullptr, nullptr, m_l, m_bf);
        // ffn2: BM=64 (grid 8x48 = 384 blocks)
        gemm_st_kernel<2><<<dim3(8, 48), 256, 0, stream>>>(
            m_bf, Wbf + WOFF_2, b2 + l * C_, M, C_, H4_, 2, nullptr, nullptr, h_f, nullptr);
        ln_kernel<<<B_ * S_, 256, 0, stream>>>(h_f, ln2_g + l * C_, ln2_b + l * C_, h_bf);
    }

    heads_kernel<<<B_ * T_, 256, 0, stream>>>(h_f, pr_w, pr_b, ps_w, ps_b, pa_w, pa_b, out);
}